// Round 12
// baseline (898.808 us; speedup 1.0000x reference)
//
#include <hip/hip_runtime.h>

// EoMT criterion v10 (DIAGNOSTIC): real v9 pipeline unchanged + ablation
// dispatches k_abl<0/1/2> (loads / +math / +MFMA, 2x chunks each) and k_match6
// (JV matcher repeated 6x into scratch). Ablations write to sinks only; output
// path identical to v9. bs=2, N=100, C+1=7, HW=512^2, M=20.

typedef unsigned int u32;
typedef __attribute__((ext_vector_type(8))) short short8;    // 8 bf16 (4 VGPRs)
typedef __attribute__((ext_vector_type(4))) float f32x4;
typedef __attribute__((ext_vector_type(4))) unsigned int u32x4;
typedef __attribute__((ext_vector_type(16))) float f32x16;

#define BS 2
#define NQ 100
#define C1 7
#define HWPX 262144
#define MG 20
#define NO_OBJ_C 6
#define NR2 128              // 4 tiles of 32 rows; rows 100..127 pad (row 100: A=1 -> ysum)
#define NTL 4
#define CH 256               // pixels per block
#define NCH (HWPX / CH)      // 1024
#define KST (CH / 16)        // 16 k-steps (K=16 per MFMA)
#define RSUB 64              // k_reduce sub-blocks per (b,tile)
#define RCH (NCH / RSUB)     // 16 chunks per reduce block
#define ABL_REP 2            // ablation kernels process 2 distinct chunks

// ---- workspace layout (bytes); harness ws ~838MB ----
static constexpr size_t OFF_PACKED = 0;                                   // u32 [BS][HWPX] = 2MB
static constexpr size_t OFF_P      = (size_t)BS * HWPX * 4;               // u32 [BS][NCH][NTL][1024] = 32MB (bf16-packed)
static constexpr size_t SZ_P       = (size_t)BS * NCH * NTL * 1024 * 4;
static constexpr size_t OFF_PLQ    = OFF_P + SZ_P;                        // f32 [BS][NCH][NTL][32] = 1MB
static constexpr size_t SZ_PLQ     = (size_t)BS * NCH * NTL * 32 * 4;
static constexpr size_t OFF_X      = OFF_PLQ + SZ_PLQ;                    // f32 [BS][128][32]
static constexpr size_t OFF_S      = OFF_X + (size_t)BS * NR2 * 32 * 4;
static constexpr size_t OFF_LQS    = OFF_S + (size_t)BS * NR2 * 32 * 4;   // f32 [BS][128]
static constexpr size_t ZERO_BYTES = (OFF_LQS + (size_t)BS * NR2 * 4) - OFF_X;  // 66560
static constexpr size_t OFF_SINK   = 256ull * 1024 * 1024;                // diagnostics scratch
static constexpr size_t SZ_SINK    = (size_t)BS * NCH * 256 * 16;         // 8MB per variant

__device__ __forceinline__ float fast_rcp(float x){
#if __has_builtin(__builtin_amdgcn_rcpf)
    return __builtin_amdgcn_rcpf(x);
#else
    return 1.0f / x;
#endif
}

// truncation pack: two f32 -> u32 of 2 bf16 (bias tiny vs 0.17 threshold; validated r7-r11)
__device__ __forceinline__ u32 pkt(float lo, float hi){
    u32 ul = __builtin_bit_cast(u32, lo), uh = __builtin_bit_cast(u32, hi);
    return (uh & 0xFFFF0000u) | (ul >> 16);
}
__device__ __forceinline__ float bflo(u32 u){ return __builtin_bit_cast(float, u << 16); }
__device__ __forceinline__ float bfhi(u32 u){ return __builtin_bit_cast(float, u & 0xFFFF0000u); }

// ---- pack 20 binary masks into one u32 per pixel + zero accum/out ----
__global__ __launch_bounds__(256) void k_pack(const int* __restrict__ gt, u32* __restrict__ packed,
                                              float* __restrict__ accum, float* __restrict__ out){
    if (blockIdx.x == 0){
        f32x4 z = {0.f, 0.f, 0.f, 0.f};
        f32x4* a4 = (f32x4*)accum;
        for (int i = threadIdx.x; i < (int)(ZERO_BYTES / 16); i += 256) a4[i] = z;
        if (threadIdx.x < 4) out[threadIdx.x] = 0.0f;
    }
    int i4 = blockIdx.x * 256 + threadIdx.x;      // 0 .. BS*HWPX/4-1
    int base = i4 * 4;
    int b = base >> 18;
    int pix = base & (HWPX - 1);
    const int* g = gt + ((size_t)b * MG << 18) + pix;
    u32 w0 = 0, w1 = 0, w2 = 0, w3 = 0;
#pragma unroll
    for (int m = 0; m < MG; m++){
        int4 v = *(const int4*)(g + ((size_t)m << 18));
        w0 |= ((u32)v.x & 1u) << m;
        w1 |= ((u32)v.y & 1u) << m;
        w2 |= ((u32)v.z & 1u) << m;
        w3 |= ((u32)v.w & 1u) << m;
    }
    *(uint4*)(packed + ((size_t)b << 18) + pix) = make_uint4(w0, w1, w2, w3);
}

// ---- heavy kernel (v9): wave = 32-row tile; barrier-free, 2-deep prefetch ----
__global__ __launch_bounds__(256, 3) void k_main(const float* __restrict__ mlog, const u32* __restrict__ pkd,
                                                 u32* __restrict__ Ppart, float* __restrict__ Plq){
    int blk = blockIdx.x;                 // [BS * NCH] = 2048
    int chunk = blk % NCH;
    int b = blk / NCH;
    int t = threadIdx.x;
    int wave = t >> 6, lane = t & 63;
    int r = lane & 31, kq = lane >> 5;
    int row = wave * 32 + r;
    bool pad = row >= NQ;
    int rowc = pad ? (NQ - 1) : row;

    const float* xp = mlog + ((size_t)b * NQ + rowc) * HWPX + chunk * CH + kq * 8;
    const u32*   wp = pkd + ((size_t)b << 18) + chunk * CH + kq * 8;

    int c = lane & 31;
    u32 shc  = (c < MG) ? (u32)c : 0u;
    u32 andm = (c < MG) ? 1u : 0u;
    u32 orm  = (c == MG) ? 1u : 0u;

    f32x16 accX = {0,0,0,0,0,0,0,0,0,0,0,0,0,0,0,0};
    f32x16 accS = {0,0,0,0,0,0,0,0,0,0,0,0,0,0,0,0};
    float lqacc = 0.0f;
    const u32x4 ones4 = {0x3F803F80u, 0x3F803F80u, 0x3F803F80u, 0x3F803F80u};

    auto bpair = [&](u32 wl, u32 wh) -> u32 {
        u32 bl = ((wl >> shc) & andm) | orm;
        u32 bh = ((wh >> shc) & andm) | orm;
        return (bl | (bh << 16)) * 0x3F80u;
    };
    auto step = [&](f32x4 XA, f32x4 XB, u32x4 WA, u32x4 WB){
        float x0=XA[0],x1=XA[1],x2=XA[2],x3=XA[3];
        float x4=XB[0],x5=XB[1],x6=XB[2],x7=XB[3];
        float e0=__expf(-x0),e1=__expf(-x1),e2=__expf(-x2),e3=__expf(-x3);
        float e4=__expf(-x4),e5=__expf(-x5),e6=__expf(-x6),e7=__expf(-x7);
        float d0=1.f+e0,d1=1.f+e1,d2=1.f+e2,d3=1.f+e3;
        float d4=1.f+e4,d5=1.f+e5,d6=1.f+e6,d7=1.f+e7;
        float p0=fast_rcp(d0),p1=fast_rcp(d1),p2=fast_rcp(d2),p3=fast_rcp(d3);
        float p4=fast_rcp(d4),p5=fast_rcp(d5),p6=fast_rcp(d6),p7=fast_rcp(d7);
        float pr = ((d0*d1)*(d2*d3))*((d4*d5)*(d6*d7));
        lqacc -= __logf(pr) + (((x0+x1)+(x2+x3))+((x4+x5)+(x6+x7)));
        u32x4 av; av[0]=pkt(x0,x1); av[1]=pkt(x2,x3); av[2]=pkt(x4,x5); av[3]=pkt(x6,x7);
        if (pad) av = ones4;
        u32x4 qv; qv[0]=pkt(p0,p1); qv[1]=pkt(p2,p3); qv[2]=pkt(p4,p5); qv[3]=pkt(p6,p7);
        u32x4 bv; bv[0]=bpair(WA[0],WA[1]); bv[1]=bpair(WA[2],WA[3]);
                  bv[2]=bpair(WB[0],WB[1]); bv[3]=bpair(WB[2],WB[3]);
        short8 Av = __builtin_bit_cast(short8, av);
        short8 Qv = __builtin_bit_cast(short8, qv);
        short8 Bv = __builtin_bit_cast(short8, bv);
        accX = __builtin_amdgcn_mfma_f32_32x32x16_bf16(Av, Bv, accX, 0, 0, 0);
        accS = __builtin_amdgcn_mfma_f32_32x32x16_bf16(Qv, Bv, accS, 0, 0, 0);
    };

    f32x4 xa0 = *(const f32x4*)(xp),      xb0 = *(const f32x4*)(xp + 4);
    u32x4 wa0 = *(const u32x4*)(wp),      wb0 = *(const u32x4*)(wp + 4);
    f32x4 xa1 = *(const f32x4*)(xp + 16), xb1 = *(const f32x4*)(xp + 20);
    u32x4 wa1 = *(const u32x4*)(wp + 16), wb1 = *(const u32x4*)(wp + 20);
#pragma unroll
    for (int s = 0; s < KST; s += 2){
        f32x4 XA = xa0, XB = xb0; u32x4 WA = wa0, WB = wb0;
        if (s + 2 < KST){
            xa0 = *(const f32x4*)(xp + (s+2)*16);      xb0 = *(const f32x4*)(xp + (s+2)*16 + 4);
            wa0 = *(const u32x4*)(wp + (s+2)*16);      wb0 = *(const u32x4*)(wp + (s+2)*16 + 4);
        }
        step(XA, XB, WA, WB);
        XA = xa1; XB = xb1; WA = wa1; WB = wb1;
        if (s + 3 < KST){
            xa1 = *(const f32x4*)(xp + (s+3)*16);      xb1 = *(const f32x4*)(xp + (s+3)*16 + 4);
            wa1 = *(const u32x4*)(wp + (s+3)*16);      wb1 = *(const u32x4*)(wp + (s+3)*16 + 4);
        }
        step(XA, XB, WA, WB);
    }

    size_t pb = (((size_t)b * NCH + chunk) * NTL + wave) * 1024;
#pragma unroll
    for (int p = 0; p < 4; p++){
        uint2 vx = make_uint2(pkt(accX[4*p], accX[4*p+1]), pkt(accX[4*p+2], accX[4*p+3]));
        uint2 vs = make_uint2(pkt(accS[4*p], accS[4*p+1]), pkt(accS[4*p+2], accS[4*p+3]));
        *(uint2*)(Ppart + pb + p*128 + lane*2) = vx;
        *(uint2*)(Ppart + pb + 512 + p*128 + lane*2) = vs;
    }
    lqacc += __shfl_xor(lqacc, 32);
    if (lane < 32) Plq[(((size_t)b * NCH + chunk) * NTL + wave) * 32 + lane] = lqacc;
}

// ---- DIAGNOSTIC: same geometry as k_main; V=0 loads-only, V=1 +math, V=2 +MFMA ----
template<int V>
__global__ __launch_bounds__(256, 3) void k_abl(const float* __restrict__ mlog, const u32* __restrict__ pkd,
                                                u32* __restrict__ sink){
    int blk = blockIdx.x;                 // [BS * NCH]
    int chunk0 = blk % NCH;
    int b = blk / NCH;
    int t = threadIdx.x;
    int wave = t >> 6, lane = t & 63;
    int r = lane & 31, kq = lane >> 5;
    int row = wave * 32 + r;
    bool pad = row >= NQ;
    int rowc = pad ? (NQ - 1) : row;
    const float* xrow = mlog + ((size_t)b * NQ + rowc) * HWPX;
    const u32*   wrow = pkd + ((size_t)b << 18);

    int c = lane & 31;
    u32 shc  = (c < MG) ? (u32)c : 0u;
    u32 andm = (c < MG) ? 1u : 0u;
    u32 orm  = (c == MG) ? 1u : 0u;

    f32x16 accX = {0,0,0,0,0,0,0,0,0,0,0,0,0,0,0,0};
    f32x16 accS = {0,0,0,0,0,0,0,0,0,0,0,0,0,0,0,0};
    u32x4 live = {0,0,0,0};
    float lqacc = 0.0f;
    const u32x4 ones4 = {0x3F803F80u, 0x3F803F80u, 0x3F803F80u, 0x3F803F80u};

    auto bpair = [&](u32 wl, u32 wh) -> u32 {
        u32 bl = ((wl >> shc) & andm) | orm;
        u32 bh = ((wh >> shc) & andm) | orm;
        return (bl | (bh << 16)) * 0x3F80u;
    };
    auto stepV = [&](f32x4 XA, f32x4 XB, u32x4 WA, u32x4 WB){
        if (V == 0){
            live ^= __builtin_bit_cast(u32x4, XA);
            live ^= __builtin_bit_cast(u32x4, XB);
            live ^= WA; live ^= WB;
            return;
        }
        float x0=XA[0],x1=XA[1],x2=XA[2],x3=XA[3];
        float x4=XB[0],x5=XB[1],x6=XB[2],x7=XB[3];
        float e0=__expf(-x0),e1=__expf(-x1),e2=__expf(-x2),e3=__expf(-x3);
        float e4=__expf(-x4),e5=__expf(-x5),e6=__expf(-x6),e7=__expf(-x7);
        float d0=1.f+e0,d1=1.f+e1,d2=1.f+e2,d3=1.f+e3;
        float d4=1.f+e4,d5=1.f+e5,d6=1.f+e6,d7=1.f+e7;
        float p0=fast_rcp(d0),p1=fast_rcp(d1),p2=fast_rcp(d2),p3=fast_rcp(d3);
        float p4=fast_rcp(d4),p5=fast_rcp(d5),p6=fast_rcp(d6),p7=fast_rcp(d7);
        float pr = ((d0*d1)*(d2*d3))*((d4*d5)*(d6*d7));
        lqacc -= __logf(pr) + (((x0+x1)+(x2+x3))+((x4+x5)+(x6+x7)));
        u32x4 av; av[0]=pkt(x0,x1); av[1]=pkt(x2,x3); av[2]=pkt(x4,x5); av[3]=pkt(x6,x7);
        if (pad) av = ones4;
        u32x4 qv; qv[0]=pkt(p0,p1); qv[1]=pkt(p2,p3); qv[2]=pkt(p4,p5); qv[3]=pkt(p6,p7);
        u32x4 bv; bv[0]=bpair(WA[0],WA[1]); bv[1]=bpair(WA[2],WA[3]);
                  bv[2]=bpair(WB[0],WB[1]); bv[3]=bpair(WB[2],WB[3]);
        if (V == 1){ live ^= av; live ^= qv; live ^= bv; return; }
        short8 Av = __builtin_bit_cast(short8, av);
        short8 Qv = __builtin_bit_cast(short8, qv);
        short8 Bv = __builtin_bit_cast(short8, bv);
        accX = __builtin_amdgcn_mfma_f32_32x32x16_bf16(Av, Bv, accX, 0, 0, 0);
        accS = __builtin_amdgcn_mfma_f32_32x32x16_bf16(Qv, Bv, accS, 0, 0, 0);
    };

    for (int rep = 0; rep < ABL_REP; ++rep){
        int chunk = (chunk0 + rep * (NCH / ABL_REP)) & (NCH - 1);
        const float* xp = xrow + chunk * CH + kq * 8;
        const u32*   wp = wrow + chunk * CH + kq * 8;
        f32x4 xa0 = *(const f32x4*)(xp),      xb0 = *(const f32x4*)(xp + 4);
        u32x4 wa0 = *(const u32x4*)(wp),      wb0 = *(const u32x4*)(wp + 4);
        f32x4 xa1 = *(const f32x4*)(xp + 16), xb1 = *(const f32x4*)(xp + 20);
        u32x4 wa1 = *(const u32x4*)(wp + 16), wb1 = *(const u32x4*)(wp + 20);
#pragma unroll
        for (int s = 0; s < KST; s += 2){
            f32x4 XA = xa0, XB = xb0; u32x4 WA = wa0, WB = wb0;
            if (s + 2 < KST){
                xa0 = *(const f32x4*)(xp + (s+2)*16);      xb0 = *(const f32x4*)(xp + (s+2)*16 + 4);
                wa0 = *(const u32x4*)(wp + (s+2)*16);      wb0 = *(const u32x4*)(wp + (s+2)*16 + 4);
            }
            stepV(XA, XB, WA, WB);
            XA = xa1; XB = xb1; WA = wa1; WB = wb1;
            if (s + 3 < KST){
                xa1 = *(const f32x4*)(xp + (s+3)*16);      xb1 = *(const f32x4*)(xp + (s+3)*16 + 4);
                wa1 = *(const u32x4*)(wp + (s+3)*16);      wb1 = *(const u32x4*)(wp + (s+3)*16 + 4);
            }
            stepV(XA, XB, WA, WB);
        }
    }

    size_t o = ((size_t)blk * 256 + t) * 4;
    if (V == 2){
        f32x4 s4;
#pragma unroll
        for (int q = 0; q < 4; q++)
            s4[q] = accX[q]+accX[4+q]+accX[8+q]+accX[12+q]
                  + accS[q]+accS[4+q]+accS[8+q]+accS[12+q];
        s4[3] += lqacc;
        *(f32x4*)((float*)sink + o) = s4;
    } else {
        u32x4 z = live;
        z[3] ^= __builtin_bit_cast(u32, lqacc);
        *(u32x4*)(sink + o) = z;
    }
}

// ---- reduce bf16 partials -> Xg/Sg/lqs ----
__global__ __launch_bounds__(256) void k_reduce(const u32* __restrict__ P, const float* __restrict__ Plq,
                                                float* __restrict__ Xg, float* __restrict__ Sg,
                                                float* __restrict__ lqs){
    int g = blockIdx.x;                   // [BS * NTL * RSUB] = 512
    int sub = g % RSUB;
    int tile = (g / RSUB) % NTL;
    int b = g / (RSUB * NTL);
    int t = threadIdx.x;
    f32x4 ax = {0,0,0,0}, as = {0,0,0,0};
    for (int i = 0; i < RCH; i++){
        int ch = sub * RCH + i;
        const u32* base = P + (((size_t)b * NCH + ch) * NTL + tile) * 1024;
        uint2 ux = *(const uint2*)(base + t*2);
        uint2 us = *(const uint2*)(base + 512 + t*2);
        ax[0] += bflo(ux.x); ax[1] += bfhi(ux.x); ax[2] += bflo(ux.y); ax[3] += bfhi(ux.y);
        as[0] += bflo(us.x); as[1] += bfhi(us.x); as[2] += bflo(us.y); as[3] += bfhi(us.y);
    }
    int p = t >> 6, l = t & 63;
    int col = l & 31;
#pragma unroll
    for (int j = 0; j < 4; j++){
        int row32 = j + 8*p + 4*(l >> 5);
        size_t o = ((size_t)b * NR2 + tile*32 + row32) * 32 + col;
        atomicAdd(&Xg[o], ax[j]);
        atomicAdd(&Sg[o], as[j]);
    }
    if (t < 32){
        float s = 0.f;
        for (int i = 0; i < RCH; i++){
            int ch = sub * RCH + i;
            s += Plq[(((size_t)b * NCH + ch) * NTL + tile) * 32 + t];
        }
        atomicAdd(&lqs[b * NR2 + tile*32 + t], s);
    }
}

// ---- fused: cost matrix + Hungarian (JV, f64, faithful) + final losses.
// REPS=1 writes to out (atomicAdd); REPS>1 is the diagnostic clone writing to scratch.
template<int REPS>
__global__ __launch_bounds__(64) void k_match(const float* __restrict__ cl, const int* __restrict__ gtc,
                                              const float* __restrict__ Xg, const float* __restrict__ Sg,
                                              const float* __restrict__ lqs, float* __restrict__ out){
    __shared__ double c[MG][NQ];
    __shared__ double u[MG + 1];
    __shared__ double v[NQ + 1];
    __shared__ double minv[NQ + 1];
    __shared__ int p[NQ + 1];
    __shared__ int way[NQ + 1];
    __shared__ int used[NQ + 1];
    int b = blockIdx.x, t = threadIdx.x;

    for (int rep = 0; rep < REPS; ++rep){
    __syncthreads();
    for (int q = t; q < NQ; q += 64){
        const float* lg = cl + ((size_t)b * NQ + q) * C1;
        float l0=lg[0],l1=lg[1],l2=lg[2],l3=lg[3],l4=lg[4],l5=lg[5],l6=lg[6];
        float mx = fmaxf(fmaxf(fmaxf(l0,l1),fmaxf(l2,l3)), fmaxf(fmaxf(l4,l5),l6));
        float e0=__expf(l0-mx),e1=__expf(l1-mx),e2=__expf(l2-mx),e3=__expf(l3-mx),
              e4=__expf(l4-mx),e5=__expf(l5-mx),e6=__expf(l6-mx);
        float inv = 1.0f / (e0+e1+e2+e3+e4+e5+e6);
        float lqv = lqs[b * NR2 + q];
        float psv = Sg[((size_t)b * NR2 + q) * 32 + 20];
#pragma unroll
        for (int m = 0; m < MG; m++){
            int cc = gtc[b * MG + m];
            float ec = (cc==0)?e0:(cc==1)?e1:(cc==2)?e2:(cc==3)?e3:(cc==4)?e4:e5;
            float Xv = Xg[((size_t)b * NR2 + q) * 32 + m];
            float Sv = Sg[((size_t)b * NR2 + q) * 32 + m];
            float ysm = Xg[((size_t)b * NR2 + 100) * 32 + m];
            float bce = -(Xv + lqv) * (1.0f / (float)HWPX);
            float dice = 1.0f - (2.0f * Sv + 1.0f) / (psv + ysm + 1.0f);
            c[m][q] = (double)(2.0f * (-ec * inv) + 5.0f * bce + 5.0f * dice);
        }
    }
    for (int j = t; j <= NQ; j += 64){ v[j] = 0.0; p[j] = 0; way[j] = 0; }
    if (t <= MG) u[t] = 0.0;
    __syncthreads();

    const double INF = 1e18;
    for (int i = 1; i <= MG; i++){
        if (t == 0) p[0] = i;
        for (int j = t; j <= NQ; j += 64){ minv[j] = INF; used[j] = 0; }
        __syncthreads();
        int j0 = 0;
        while (true){
            if (t == 0) used[j0] = 1;
            __syncthreads();
            int i0 = p[j0];
            double du = u[i0];
            for (int j = t + 1; j <= NQ; j += 64){
                if (!used[j]){
                    double cand = c[i0 - 1][j - 1] - du - v[j];
                    if (cand < minv[j]){ minv[j] = cand; way[j] = j0; }
                }
            }
            __syncthreads();
            double best = INF; int bj = NQ + 1;
            for (int j = t + 1; j <= NQ; j += 64){
                double mv = used[j] ? INF : minv[j];
                if (mv < best || (mv == best && j < bj)){ best = mv; bj = j; }
            }
#pragma unroll
            for (int off = 32; off; off >>= 1){
                double ob = __shfl_xor(best, off);
                int    oj = __shfl_xor(bj, off);
                if (ob < best || (ob == best && oj < bj)){ best = ob; bj = oj; }
            }
            int j1 = bj;
            double delta = best;
            for (int j = t; j <= NQ; j += 64){
                if (used[j]){ u[p[j]] += delta; v[j] -= delta; }
                else        { minv[j] -= delta; }
            }
            __syncthreads();
            j0 = j1;
            if (p[j0] == 0) break;
        }
        if (t == 0){
            int jj = j0;
            while (jj){ int jn = way[jj]; p[jj] = p[jn]; jj = jn; }
        }
        __syncthreads();
    }

    float wnll = 0.f, wsum = 0.f, bsum = 0.f, dsum = 0.f;
    for (int q = t; q < NQ; q += 64){
        int pi = p[q + 1];
        int tg = (pi != 0) ? gtc[b * MG + (pi - 1)] : NO_OBJ_C;
        const float* lg = cl + ((size_t)b * NQ + q) * C1;
        float l0=lg[0],l1=lg[1],l2=lg[2],l3=lg[3],l4=lg[4],l5=lg[5],l6=lg[6];
        float mx = fmaxf(fmaxf(fmaxf(l0,l1),fmaxf(l2,l3)), fmaxf(fmaxf(l4,l5),l6));
        float se = __expf(l0-mx)+__expf(l1-mx)+__expf(l2-mx)+__expf(l3-mx)
                 + __expf(l4-mx)+__expf(l5-mx)+__expf(l6-mx);
        float lse = __logf(se) + mx;
        float lt = (tg==0)?l0:(tg==1)?l1:(tg==2)?l2:(tg==3)?l3:(tg==4)?l4:(tg==5)?l5:l6;
        float w = (tg == NO_OBJ_C) ? 0.1f : 1.0f;
        wnll += w * (lse - lt);
        wsum += w;
        if (pi != 0){
            int k = pi - 1;
            float Xv  = Xg[((size_t)b * NR2 + q) * 32 + k];
            float Sv  = Sg[((size_t)b * NR2 + q) * 32 + k];
            float lqv = lqs[b * NR2 + q];
            float psv = Sg[((size_t)b * NR2 + q) * 32 + 20];
            float ysm = Xg[((size_t)b * NR2 + 100) * 32 + k];
            bsum += -(Xv + lqv);
            dsum += 1.0f - (2.0f * Sv + 1.0f) / (psv + ysm + 1.0f);
        }
    }
#pragma unroll
    for (int off = 32; off; off >>= 1){
        wnll += __shfl_xor(wnll, off);
        wsum += __shfl_xor(wsum, off);
        bsum += __shfl_xor(bsum, off);
        dsum += __shfl_xor(dsum, off);
    }
    if (t == 0){
        float tc = wnll / wsum;
        float tm = bsum / ((float)MG * (float)HWPX);
        float td = dsum / (float)MG;
        if (REPS == 1){
            atomicAdd(&out[0], 0.5f * tc);
            atomicAdd(&out[1], 0.5f * tm);
            atomicAdd(&out[2], 0.5f * td);
            atomicAdd(&out[3], 0.5f * (2.0f * tc + 5.0f * tm + 5.0f * td));
        } else {
            float* dst = out + ((size_t)rep * BS + b) * 4;
            dst[0] = tc; dst[1] = tm; dst[2] = td;
            dst[3] = 2.0f * tc + 5.0f * tm + 5.0f * td;
        }
    }
    }
}

extern "C" void kernel_launch(void* const* d_in, const int* in_sizes, int n_in,
                              void* d_out, int out_size, void* d_ws, size_t ws_size,
                              hipStream_t stream){
    const float* cls_logits  = (const float*)d_in[0];
    const float* mask_logits = (const float*)d_in[1];
    const int*   gt_classes  = (const int*)d_in[2];
    const int*   gt_masks    = (const int*)d_in[3];
    float* out = (float*)d_out;
    char* ws = (char*)d_ws;

    u32*   packed = (u32*)  (ws + OFF_PACKED);
    u32*   Ppart  = (u32*)  (ws + OFF_P);
    float* Plq    = (float*)(ws + OFF_PLQ);
    float* Xg     = (float*)(ws + OFF_X);
    float* Sg     = (float*)(ws + OFF_S);
    float* lqs    = (float*)(ws + OFF_LQS);
    u32*   sink0  = (u32*)  (ws + OFF_SINK);
    u32*   sink1  = (u32*)  (ws + OFF_SINK + SZ_SINK);
    u32*   sink2  = (u32*)  (ws + OFF_SINK + 2*SZ_SINK);
    float* msink  = (float*)(ws + OFF_SINK + 3*SZ_SINK);

    // real pipeline (v9)
    k_pack  <<<dim3(BS * HWPX / 1024), dim3(256), 0, stream>>>(gt_masks, packed, Xg, out);
    k_main  <<<dim3(BS * NCH),         dim3(256), 0, stream>>>(mask_logits, packed, Ppart, Plq);
    k_reduce<<<dim3(BS * NTL * RSUB),  dim3(256), 0, stream>>>(Ppart, Plq, Xg, Sg, lqs);
    k_match<1><<<dim3(BS),             dim3(64),  0, stream>>>(cls_logits, gt_classes, Xg, Sg, lqs, out);

    // diagnostics (write scratch only; deterministic)
    k_abl<0><<<dim3(BS * NCH), dim3(256), 0, stream>>>(mask_logits, packed, sink0);
    k_abl<1><<<dim3(BS * NCH), dim3(256), 0, stream>>>(mask_logits, packed, sink1);
    k_abl<2><<<dim3(BS * NCH), dim3(256), 0, stream>>>(mask_logits, packed, sink2);
    k_match<6><<<dim3(BS),     dim3(64),  0, stream>>>(cls_logits, gt_classes, Xg, Sg, lqs, msink);
}

// Round 13
// 128.454 us; speedup vs baseline: 6.9971x; 6.9971x over previous
//
#include <hip/hip_runtime.h>

// EoMT criterion v11: v9 pipeline + register-resident Jonker-Volgenant k_match
// (columns in lane registers, u via inTree flag, cost in LDS, f64 semantics).
// bs=2, N=100, C+1=7, HW=512^2, M=20.

typedef unsigned int u32;
typedef __attribute__((ext_vector_type(8))) short short8;    // 8 bf16 (4 VGPRs)
typedef __attribute__((ext_vector_type(4))) float f32x4;
typedef __attribute__((ext_vector_type(4))) unsigned int u32x4;
typedef __attribute__((ext_vector_type(16))) float f32x16;

#define BS 2
#define NQ 100
#define C1 7
#define HWPX 262144
#define MG 20
#define NO_OBJ_C 6
#define NR2 128              // 4 tiles of 32 rows; rows 100..127 pad (row 100: A=1 -> ysum)
#define NTL 4
#define CH 256               // pixels per block
#define NCH (HWPX / CH)      // 1024
#define KST (CH / 16)        // 16 k-steps (K=16 per MFMA)
#define RSUB 64              // k_reduce sub-blocks per (b,tile)
#define RCH (NCH / RSUB)     // 16 chunks per reduce block

// ---- workspace layout (bytes); harness ws ~838MB ----
static constexpr size_t OFF_PACKED = 0;                                   // u32 [BS][HWPX] = 2MB
static constexpr size_t OFF_P      = (size_t)BS * HWPX * 4;               // u32 [BS][NCH][NTL][1024] = 32MB (bf16-packed)
static constexpr size_t SZ_P       = (size_t)BS * NCH * NTL * 1024 * 4;
static constexpr size_t OFF_PLQ    = OFF_P + SZ_P;                        // f32 [BS][NCH][NTL][32] = 1MB
static constexpr size_t SZ_PLQ     = (size_t)BS * NCH * NTL * 32 * 4;
static constexpr size_t OFF_X      = OFF_PLQ + SZ_PLQ;                    // f32 [BS][128][32]
static constexpr size_t OFF_S      = OFF_X + (size_t)BS * NR2 * 32 * 4;
static constexpr size_t OFF_LQS    = OFF_S + (size_t)BS * NR2 * 32 * 4;   // f32 [BS][128]
static constexpr size_t ZERO_BYTES = (OFF_LQS + (size_t)BS * NR2 * 4) - OFF_X;  // 66560

__device__ __forceinline__ float fast_rcp(float x){
#if __has_builtin(__builtin_amdgcn_rcpf)
    return __builtin_amdgcn_rcpf(x);
#else
    return 1.0f / x;
#endif
}

// truncation pack: two f32 -> u32 of 2 bf16 (bias tiny vs 0.17 threshold; validated r7-r12)
__device__ __forceinline__ u32 pkt(float lo, float hi){
    u32 ul = __builtin_bit_cast(u32, lo), uh = __builtin_bit_cast(u32, hi);
    return (uh & 0xFFFF0000u) | (ul >> 16);
}
__device__ __forceinline__ float bflo(u32 u){ return __builtin_bit_cast(float, u << 16); }
__device__ __forceinline__ float bfhi(u32 u){ return __builtin_bit_cast(float, u & 0xFFFF0000u); }

// ---- pack 20 binary masks into one u32 per pixel + zero accum/out ----
__global__ __launch_bounds__(256) void k_pack(const int* __restrict__ gt, u32* __restrict__ packed,
                                              float* __restrict__ accum, float* __restrict__ out){
    if (blockIdx.x == 0){
        f32x4 z = {0.f, 0.f, 0.f, 0.f};
        f32x4* a4 = (f32x4*)accum;
        for (int i = threadIdx.x; i < (int)(ZERO_BYTES / 16); i += 256) a4[i] = z;
        if (threadIdx.x < 4) out[threadIdx.x] = 0.0f;
    }
    int i4 = blockIdx.x * 256 + threadIdx.x;      // 0 .. BS*HWPX/4-1
    int base = i4 * 4;
    int b = base >> 18;
    int pix = base & (HWPX - 1);
    const int* g = gt + ((size_t)b * MG << 18) + pix;
    u32 w0 = 0, w1 = 0, w2 = 0, w3 = 0;
#pragma unroll
    for (int m = 0; m < MG; m++){
        int4 v = *(const int4*)(g + ((size_t)m << 18));
        w0 |= ((u32)v.x & 1u) << m;
        w1 |= ((u32)v.y & 1u) << m;
        w2 |= ((u32)v.z & 1u) << m;
        w3 |= ((u32)v.w & 1u) << m;
    }
    *(uint4*)(packed + ((size_t)b << 18) + pix) = make_uint4(w0, w1, w2, w3);
}

// ---- heavy kernel (v9): wave = 32-row tile; barrier-free, 2-deep prefetch ----
__global__ __launch_bounds__(256, 3) void k_main(const float* __restrict__ mlog, const u32* __restrict__ pkd,
                                                 u32* __restrict__ Ppart, float* __restrict__ Plq){
    int blk = blockIdx.x;                 // [BS * NCH] = 2048
    int chunk = blk % NCH;
    int b = blk / NCH;
    int t = threadIdx.x;
    int wave = t >> 6, lane = t & 63;
    int r = lane & 31, kq = lane >> 5;
    int row = wave * 32 + r;
    bool pad = row >= NQ;
    int rowc = pad ? (NQ - 1) : row;

    const float* xp = mlog + ((size_t)b * NQ + rowc) * HWPX + chunk * CH + kq * 8;
    const u32*   wp = pkd + ((size_t)b << 18) + chunk * CH + kq * 8;

    int c = lane & 31;
    u32 shc  = (c < MG) ? (u32)c : 0u;
    u32 andm = (c < MG) ? 1u : 0u;
    u32 orm  = (c == MG) ? 1u : 0u;

    f32x16 accX = {0,0,0,0,0,0,0,0,0,0,0,0,0,0,0,0};
    f32x16 accS = {0,0,0,0,0,0,0,0,0,0,0,0,0,0,0,0};
    float lqacc = 0.0f;
    const u32x4 ones4 = {0x3F803F80u, 0x3F803F80u, 0x3F803F80u, 0x3F803F80u};

    auto bpair = [&](u32 wl, u32 wh) -> u32 {
        u32 bl = ((wl >> shc) & andm) | orm;
        u32 bh = ((wh >> shc) & andm) | orm;
        return (bl | (bh << 16)) * 0x3F80u;
    };
    auto step = [&](f32x4 XA, f32x4 XB, u32x4 WA, u32x4 WB){
        float x0=XA[0],x1=XA[1],x2=XA[2],x3=XA[3];
        float x4=XB[0],x5=XB[1],x6=XB[2],x7=XB[3];
        float e0=__expf(-x0),e1=__expf(-x1),e2=__expf(-x2),e3=__expf(-x3);
        float e4=__expf(-x4),e5=__expf(-x5),e6=__expf(-x6),e7=__expf(-x7);
        float d0=1.f+e0,d1=1.f+e1,d2=1.f+e2,d3=1.f+e3;
        float d4=1.f+e4,d5=1.f+e5,d6=1.f+e6,d7=1.f+e7;
        float p0=fast_rcp(d0),p1=fast_rcp(d1),p2=fast_rcp(d2),p3=fast_rcp(d3);
        float p4=fast_rcp(d4),p5=fast_rcp(d5),p6=fast_rcp(d6),p7=fast_rcp(d7);
        float pr = ((d0*d1)*(d2*d3))*((d4*d5)*(d6*d7));
        lqacc -= __logf(pr) + (((x0+x1)+(x2+x3))+((x4+x5)+(x6+x7)));
        u32x4 av; av[0]=pkt(x0,x1); av[1]=pkt(x2,x3); av[2]=pkt(x4,x5); av[3]=pkt(x6,x7);
        if (pad) av = ones4;
        u32x4 qv; qv[0]=pkt(p0,p1); qv[1]=pkt(p2,p3); qv[2]=pkt(p4,p5); qv[3]=pkt(p6,p7);
        u32x4 bv; bv[0]=bpair(WA[0],WA[1]); bv[1]=bpair(WA[2],WA[3]);
                  bv[2]=bpair(WB[0],WB[1]); bv[3]=bpair(WB[2],WB[3]);
        short8 Av = __builtin_bit_cast(short8, av);
        short8 Qv = __builtin_bit_cast(short8, qv);
        short8 Bv = __builtin_bit_cast(short8, bv);
        accX = __builtin_amdgcn_mfma_f32_32x32x16_bf16(Av, Bv, accX, 0, 0, 0);
        accS = __builtin_amdgcn_mfma_f32_32x32x16_bf16(Qv, Bv, accS, 0, 0, 0);
    };

    f32x4 xa0 = *(const f32x4*)(xp),      xb0 = *(const f32x4*)(xp + 4);
    u32x4 wa0 = *(const u32x4*)(wp),      wb0 = *(const u32x4*)(wp + 4);
    f32x4 xa1 = *(const f32x4*)(xp + 16), xb1 = *(const f32x4*)(xp + 20);
    u32x4 wa1 = *(const u32x4*)(wp + 16), wb1 = *(const u32x4*)(wp + 20);
#pragma unroll
    for (int s = 0; s < KST; s += 2){
        f32x4 XA = xa0, XB = xb0; u32x4 WA = wa0, WB = wb0;
        if (s + 2 < KST){
            xa0 = *(const f32x4*)(xp + (s+2)*16);      xb0 = *(const f32x4*)(xp + (s+2)*16 + 4);
            wa0 = *(const u32x4*)(wp + (s+2)*16);      wb0 = *(const u32x4*)(wp + (s+2)*16 + 4);
        }
        step(XA, XB, WA, WB);
        XA = xa1; XB = xb1; WA = wa1; WB = wb1;
        if (s + 3 < KST){
            xa1 = *(const f32x4*)(xp + (s+3)*16);      xb1 = *(const f32x4*)(xp + (s+3)*16 + 4);
            wa1 = *(const u32x4*)(wp + (s+3)*16);      wb1 = *(const u32x4*)(wp + (s+3)*16 + 4);
        }
        step(XA, XB, WA, WB);
    }

    size_t pb = (((size_t)b * NCH + chunk) * NTL + wave) * 1024;
#pragma unroll
    for (int p = 0; p < 4; p++){
        uint2 vx = make_uint2(pkt(accX[4*p], accX[4*p+1]), pkt(accX[4*p+2], accX[4*p+3]));
        uint2 vs = make_uint2(pkt(accS[4*p], accS[4*p+1]), pkt(accS[4*p+2], accS[4*p+3]));
        *(uint2*)(Ppart + pb + p*128 + lane*2) = vx;
        *(uint2*)(Ppart + pb + 512 + p*128 + lane*2) = vs;
    }
    lqacc += __shfl_xor(lqacc, 32);
    if (lane < 32) Plq[(((size_t)b * NCH + chunk) * NTL + wave) * 32 + lane] = lqacc;
}

// ---- reduce bf16 partials -> Xg/Sg/lqs ----
__global__ __launch_bounds__(256) void k_reduce(const u32* __restrict__ P, const float* __restrict__ Plq,
                                                float* __restrict__ Xg, float* __restrict__ Sg,
                                                float* __restrict__ lqs){
    int g = blockIdx.x;                   // [BS * NTL * RSUB] = 512
    int sub = g % RSUB;
    int tile = (g / RSUB) % NTL;
    int b = g / (RSUB * NTL);
    int t = threadIdx.x;
    f32x4 ax = {0,0,0,0}, as = {0,0,0,0};
    for (int i = 0; i < RCH; i++){
        int ch = sub * RCH + i;
        const u32* base = P + (((size_t)b * NCH + ch) * NTL + tile) * 1024;
        uint2 ux = *(const uint2*)(base + t*2);
        uint2 us = *(const uint2*)(base + 512 + t*2);
        ax[0] += bflo(ux.x); ax[1] += bfhi(ux.x); ax[2] += bflo(ux.y); ax[3] += bfhi(ux.y);
        as[0] += bflo(us.x); as[1] += bfhi(us.x); as[2] += bflo(us.y); as[3] += bfhi(us.y);
    }
    int p = t >> 6, l = t & 63;
    int col = l & 31;
#pragma unroll
    for (int j = 0; j < 4; j++){
        int row32 = j + 8*p + 4*(l >> 5);
        size_t o = ((size_t)b * NR2 + tile*32 + row32) * 32 + col;
        atomicAdd(&Xg[o], ax[j]);
        atomicAdd(&Sg[o], as[j]);
    }
    if (t < 32){
        float s = 0.f;
        for (int i = 0; i < RCH; i++){
            int ch = sub * RCH + i;
            s += Plq[(((size_t)b * NCH + ch) * NTL + tile) * 32 + t];
        }
        atomicAdd(&lqs[b * NR2 + tile*32 + t], s);
    }
}

// ---- register-resident Jonker-Volgenant + losses (1 wave per image) ----
// Lane t owns columns jA=t+1 and jB=t+65 (jB valid iff t<36); lane l (<20)
// owns u[l+1] and inTree flag. Cost matrix in LDS (dynamic row index only).
__global__ __launch_bounds__(64) void k_match(const float* __restrict__ cl, const int* __restrict__ gtc,
                                              const float* __restrict__ Xg, const float* __restrict__ Sg,
                                              const float* __restrict__ lqs, float* __restrict__ out){
    __shared__ double c[MG][NQ];          // 16 KB
    int b = blockIdx.x, t = threadIdx.x;
    bool hasB = (t < NQ - 64);            // t < 36

    // phase 1: cost (same f32 math as r3-r12, upcast to f64 like the reference)
    for (int q = t; q < NQ; q += 64){
        const float* lg = cl + ((size_t)b * NQ + q) * C1;
        float l0=lg[0],l1=lg[1],l2=lg[2],l3=lg[3],l4=lg[4],l5=lg[5],l6=lg[6];
        float mx = fmaxf(fmaxf(fmaxf(l0,l1),fmaxf(l2,l3)), fmaxf(fmaxf(l4,l5),l6));
        float e0=__expf(l0-mx),e1=__expf(l1-mx),e2=__expf(l2-mx),e3=__expf(l3-mx),
              e4=__expf(l4-mx),e5=__expf(l5-mx),e6=__expf(l6-mx);
        float inv = 1.0f / (e0+e1+e2+e3+e4+e5+e6);
        float lqv = lqs[b * NR2 + q];
        float psv = Sg[((size_t)b * NR2 + q) * 32 + 20];
#pragma unroll
        for (int m = 0; m < MG; m++){
            int cc = gtc[b * MG + m];
            float ec = (cc==0)?e0:(cc==1)?e1:(cc==2)?e2:(cc==3)?e3:(cc==4)?e4:e5;
            float Xv = Xg[((size_t)b * NR2 + q) * 32 + m];
            float Sv = Sg[((size_t)b * NR2 + q) * 32 + m];
            float ysm = Xg[((size_t)b * NR2 + 100) * 32 + m];
            float bce = -(Xv + lqv) * (1.0f / (float)HWPX);
            float dice = 1.0f - (2.0f * Sv + 1.0f) / (psv + ysm + 1.0f);
            c[m][q] = (double)(2.0f * (-ec * inv) + 5.0f * bce + 5.0f * dice);
        }
    }
    __syncthreads();

    // phase 2: JV in registers
    const double INF = 1e18;
    double vA = 0.0, vB = 0.0, u_r = 0.0;
    int pA = 0, pB = 0;

    for (int i = 1; i <= MG; i++){
        double minvA = INF, minvB = INF;
        int wayA = 0, wayB = 0;
        bool usedA = false, usedB = false;
        bool inTree = (t == i - 1);
        int j0 = 0, i0 = i;
        while (true){
            inTree = inTree || (t == i0 - 1);
            double du = __shfl(u_r, i0 - 1);
            const double* crow = &c[i0 - 1][0];
            double cA = crow[t];
            double cB = hasB ? crow[t + 64] : 0.0;
            double candA = cA - du - vA;
            double candB = cB - du - vB;
            if (!usedA && candA < minvA){ minvA = candA; wayA = j0; }
            if (hasB && !usedB && candB < minvB){ minvB = candB; wayB = j0; }
            // argmin over unused cols (first-index tie-break, like np.argmin)
            double mA = usedA ? INF : minvA;
            double mB = (hasB && !usedB) ? minvB : INF;
            double best = mA; int bcol = t + 1;
            if (mB < best){ best = mB; bcol = t + 65; }
#pragma unroll
            for (int off = 32; off; off >>= 1){
                double ob = __shfl_xor(best, off);
                int    oc = __shfl_xor(bcol, off);
                if (ob < best || (ob == best && oc < bcol)){ best = ob; bcol = oc; }
            }
            double delta = best;
            int j1 = bcol;
            // register-local updates (u scatter handled by inTree flag)
            if (inTree) u_r += delta;
            if (usedA) vA -= delta; else minvA -= delta;
            if (hasB){ if (usedB) vB -= delta; else minvB -= delta; }
            j0 = j1;
            // mark used, read p[j0]
            usedA = usedA || (t == j0 - 1);
            usedB = usedB || (t == j0 - 65);
            int own = (j0 <= 64) ? (j0 - 1) : (j0 - 65);
            int pj = __shfl((j0 <= 64) ? pA : pB, own);
            if (pj == 0) break;
            i0 = pj;
        }
        // augment: p[j0] = p[way[j0]] chain (p[0] == i)
        int cur = j0;
        while (cur){
            int own = (cur <= 64) ? (cur - 1) : (cur - 65);
            int w = __shfl((cur <= 64) ? wayA : wayB, own);
            int pv;
            if (w == 0) pv = i;
            else {
                int own2 = (w <= 64) ? (w - 1) : (w - 65);
                pv = __shfl((w <= 64) ? pA : pB, own2);
            }
            if (cur <= 64){ if (t == cur - 1) pA = pv; }
            else          { if (t == cur - 65) pB = pv; }
            cur = w;
        }
    }

    // phase 3: losses; lane handles q=t (pA) and q=t+64 (pB)
    float wnll = 0.f, wsum = 0.f, bsum = 0.f, dsum = 0.f;
#pragma unroll
    for (int slot = 0; slot < 2; slot++){
        int q = t + slot * 64;
        if (q >= NQ) break;
        int pi = slot ? pB : pA;
        int tg = (pi != 0) ? gtc[b * MG + (pi - 1)] : NO_OBJ_C;
        const float* lg = cl + ((size_t)b * NQ + q) * C1;
        float l0=lg[0],l1=lg[1],l2=lg[2],l3=lg[3],l4=lg[4],l5=lg[5],l6=lg[6];
        float mx = fmaxf(fmaxf(fmaxf(l0,l1),fmaxf(l2,l3)), fmaxf(fmaxf(l4,l5),l6));
        float se = __expf(l0-mx)+__expf(l1-mx)+__expf(l2-mx)+__expf(l3-mx)
                 + __expf(l4-mx)+__expf(l5-mx)+__expf(l6-mx);
        float lse = __logf(se) + mx;
        float lt = (tg==0)?l0:(tg==1)?l1:(tg==2)?l2:(tg==3)?l3:(tg==4)?l4:(tg==5)?l5:l6;
        float w = (tg == NO_OBJ_C) ? 0.1f : 1.0f;
        wnll += w * (lse - lt);
        wsum += w;
        if (pi != 0){
            int k = pi - 1;
            float Xv  = Xg[((size_t)b * NR2 + q) * 32 + k];
            float Sv  = Sg[((size_t)b * NR2 + q) * 32 + k];
            float lqv = lqs[b * NR2 + q];
            float psv = Sg[((size_t)b * NR2 + q) * 32 + 20];
            float ysm = Xg[((size_t)b * NR2 + 100) * 32 + k];
            bsum += -(Xv + lqv);
            dsum += 1.0f - (2.0f * Sv + 1.0f) / (psv + ysm + 1.0f);
        }
    }
#pragma unroll
    for (int off = 32; off; off >>= 1){
        wnll += __shfl_xor(wnll, off);
        wsum += __shfl_xor(wsum, off);
        bsum += __shfl_xor(bsum, off);
        dsum += __shfl_xor(dsum, off);
    }
    if (t == 0){
        float tc = wnll / wsum;
        float tm = bsum / ((float)MG * (float)HWPX);
        float td = dsum / (float)MG;
        atomicAdd(&out[0], 0.5f * tc);
        atomicAdd(&out[1], 0.5f * tm);
        atomicAdd(&out[2], 0.5f * td);
        atomicAdd(&out[3], 0.5f * (2.0f * tc + 5.0f * tm + 5.0f * td));
    }
}

extern "C" void kernel_launch(void* const* d_in, const int* in_sizes, int n_in,
                              void* d_out, int out_size, void* d_ws, size_t ws_size,
                              hipStream_t stream){
    const float* cls_logits  = (const float*)d_in[0];
    const float* mask_logits = (const float*)d_in[1];
    const int*   gt_classes  = (const int*)d_in[2];
    const int*   gt_masks    = (const int*)d_in[3];
    float* out = (float*)d_out;
    char* ws = (char*)d_ws;

    u32*   packed = (u32*)  (ws + OFF_PACKED);
    u32*   Ppart  = (u32*)  (ws + OFF_P);
    float* Plq    = (float*)(ws + OFF_PLQ);
    float* Xg     = (float*)(ws + OFF_X);
    float* Sg     = (float*)(ws + OFF_S);
    float* lqs    = (float*)(ws + OFF_LQS);

    k_pack  <<<dim3(BS * HWPX / 1024), dim3(256), 0, stream>>>(gt_masks, packed, Xg, out);
    k_main  <<<dim3(BS * NCH),         dim3(256), 0, stream>>>(mask_logits, packed, Ppart, Plq);
    k_reduce<<<dim3(BS * NTL * RSUB),  dim3(256), 0, stream>>>(Ppart, Plq, Xg, Sg, lqs);
    k_match <<<dim3(BS),               dim3(64),  0, stream>>>(cls_logits, gt_classes, Xg, Sg, lqs, out);
}

// Round 14
// 125.768 us; speedup vs baseline: 7.1466x; 1.0214x over previous
//
#include <hip/hip_runtime.h>

// EoMT criterion v12: v11 with f32 register-resident Jonker-Volgenant
// (unique-optimum argument: any exact LSA on the same costs = scipy's result;
// f32 dual arithmetic safe at random-normal margins). Rest identical to v11.
// bs=2, N=100, C+1=7, HW=512^2, M=20.

typedef unsigned int u32;
typedef __attribute__((ext_vector_type(8))) short short8;    // 8 bf16 (4 VGPRs)
typedef __attribute__((ext_vector_type(4))) float f32x4;
typedef __attribute__((ext_vector_type(4))) unsigned int u32x4;
typedef __attribute__((ext_vector_type(16))) float f32x16;

#define BS 2
#define NQ 100
#define C1 7
#define HWPX 262144
#define MG 20
#define NO_OBJ_C 6
#define NR2 128              // 4 tiles of 32 rows; rows 100..127 pad (row 100: A=1 -> ysum)
#define NTL 4
#define CH 256               // pixels per block
#define NCH (HWPX / CH)      // 1024
#define KST (CH / 16)        // 16 k-steps (K=16 per MFMA)
#define RSUB 64              // k_reduce sub-blocks per (b,tile)
#define RCH (NCH / RSUB)     // 16 chunks per reduce block

// ---- workspace layout (bytes); harness ws ~838MB ----
static constexpr size_t OFF_PACKED = 0;                                   // u32 [BS][HWPX] = 2MB
static constexpr size_t OFF_P      = (size_t)BS * HWPX * 4;               // u32 [BS][NCH][NTL][1024] = 32MB (bf16-packed)
static constexpr size_t SZ_P       = (size_t)BS * NCH * NTL * 1024 * 4;
static constexpr size_t OFF_PLQ    = OFF_P + SZ_P;                        // f32 [BS][NCH][NTL][32] = 1MB
static constexpr size_t SZ_PLQ     = (size_t)BS * NCH * NTL * 32 * 4;
static constexpr size_t OFF_X      = OFF_PLQ + SZ_PLQ;                    // f32 [BS][128][32]
static constexpr size_t OFF_S      = OFF_X + (size_t)BS * NR2 * 32 * 4;
static constexpr size_t OFF_LQS    = OFF_S + (size_t)BS * NR2 * 32 * 4;   // f32 [BS][128]
static constexpr size_t ZERO_BYTES = (OFF_LQS + (size_t)BS * NR2 * 4) - OFF_X;  // 66560

__device__ __forceinline__ float fast_rcp(float x){
#if __has_builtin(__builtin_amdgcn_rcpf)
    return __builtin_amdgcn_rcpf(x);
#else
    return 1.0f / x;
#endif
}

// truncation pack: two f32 -> u32 of 2 bf16 (bias tiny vs 0.17 threshold; validated r7-r13)
__device__ __forceinline__ u32 pkt(float lo, float hi){
    u32 ul = __builtin_bit_cast(u32, lo), uh = __builtin_bit_cast(u32, hi);
    return (uh & 0xFFFF0000u) | (ul >> 16);
}
__device__ __forceinline__ float bflo(u32 u){ return __builtin_bit_cast(float, u << 16); }
__device__ __forceinline__ float bfhi(u32 u){ return __builtin_bit_cast(float, u & 0xFFFF0000u); }

// ---- pack 20 binary masks into one u32 per pixel + zero accum/out ----
__global__ __launch_bounds__(256) void k_pack(const int* __restrict__ gt, u32* __restrict__ packed,
                                              float* __restrict__ accum, float* __restrict__ out){
    if (blockIdx.x == 0){
        f32x4 z = {0.f, 0.f, 0.f, 0.f};
        f32x4* a4 = (f32x4*)accum;
        for (int i = threadIdx.x; i < (int)(ZERO_BYTES / 16); i += 256) a4[i] = z;
        if (threadIdx.x < 4) out[threadIdx.x] = 0.0f;
    }
    int i4 = blockIdx.x * 256 + threadIdx.x;      // 0 .. BS*HWPX/4-1
    int base = i4 * 4;
    int b = base >> 18;
    int pix = base & (HWPX - 1);
    const int* g = gt + ((size_t)b * MG << 18) + pix;
    u32 w0 = 0, w1 = 0, w2 = 0, w3 = 0;
#pragma unroll
    for (int m = 0; m < MG; m++){
        int4 v = *(const int4*)(g + ((size_t)m << 18));
        w0 |= ((u32)v.x & 1u) << m;
        w1 |= ((u32)v.y & 1u) << m;
        w2 |= ((u32)v.z & 1u) << m;
        w3 |= ((u32)v.w & 1u) << m;
    }
    *(uint4*)(packed + ((size_t)b << 18) + pix) = make_uint4(w0, w1, w2, w3);
}

// ---- heavy kernel (v9): wave = 32-row tile; barrier-free, 2-deep prefetch ----
__global__ __launch_bounds__(256, 3) void k_main(const float* __restrict__ mlog, const u32* __restrict__ pkd,
                                                 u32* __restrict__ Ppart, float* __restrict__ Plq){
    int blk = blockIdx.x;                 // [BS * NCH] = 2048
    int chunk = blk % NCH;
    int b = blk / NCH;
    int t = threadIdx.x;
    int wave = t >> 6, lane = t & 63;
    int r = lane & 31, kq = lane >> 5;
    int row = wave * 32 + r;
    bool pad = row >= NQ;
    int rowc = pad ? (NQ - 1) : row;

    const float* xp = mlog + ((size_t)b * NQ + rowc) * HWPX + chunk * CH + kq * 8;
    const u32*   wp = pkd + ((size_t)b << 18) + chunk * CH + kq * 8;

    int c = lane & 31;
    u32 shc  = (c < MG) ? (u32)c : 0u;
    u32 andm = (c < MG) ? 1u : 0u;
    u32 orm  = (c == MG) ? 1u : 0u;

    f32x16 accX = {0,0,0,0,0,0,0,0,0,0,0,0,0,0,0,0};
    f32x16 accS = {0,0,0,0,0,0,0,0,0,0,0,0,0,0,0,0};
    float lqacc = 0.0f;
    const u32x4 ones4 = {0x3F803F80u, 0x3F803F80u, 0x3F803F80u, 0x3F803F80u};

    auto bpair = [&](u32 wl, u32 wh) -> u32 {
        u32 bl = ((wl >> shc) & andm) | orm;
        u32 bh = ((wh >> shc) & andm) | orm;
        return (bl | (bh << 16)) * 0x3F80u;
    };
    auto step = [&](f32x4 XA, f32x4 XB, u32x4 WA, u32x4 WB){
        float x0=XA[0],x1=XA[1],x2=XA[2],x3=XA[3];
        float x4=XB[0],x5=XB[1],x6=XB[2],x7=XB[3];
        float e0=__expf(-x0),e1=__expf(-x1),e2=__expf(-x2),e3=__expf(-x3);
        float e4=__expf(-x4),e5=__expf(-x5),e6=__expf(-x6),e7=__expf(-x7);
        float d0=1.f+e0,d1=1.f+e1,d2=1.f+e2,d3=1.f+e3;
        float d4=1.f+e4,d5=1.f+e5,d6=1.f+e6,d7=1.f+e7;
        float p0=fast_rcp(d0),p1=fast_rcp(d1),p2=fast_rcp(d2),p3=fast_rcp(d3);
        float p4=fast_rcp(d4),p5=fast_rcp(d5),p6=fast_rcp(d6),p7=fast_rcp(d7);
        float pr = ((d0*d1)*(d2*d3))*((d4*d5)*(d6*d7));
        lqacc -= __logf(pr) + (((x0+x1)+(x2+x3))+((x4+x5)+(x6+x7)));
        u32x4 av; av[0]=pkt(x0,x1); av[1]=pkt(x2,x3); av[2]=pkt(x4,x5); av[3]=pkt(x6,x7);
        if (pad) av = ones4;
        u32x4 qv; qv[0]=pkt(p0,p1); qv[1]=pkt(p2,p3); qv[2]=pkt(p4,p5); qv[3]=pkt(p6,p7);
        u32x4 bv; bv[0]=bpair(WA[0],WA[1]); bv[1]=bpair(WA[2],WA[3]);
                  bv[2]=bpair(WB[0],WB[1]); bv[3]=bpair(WB[2],WB[3]);
        short8 Av = __builtin_bit_cast(short8, av);
        short8 Qv = __builtin_bit_cast(short8, qv);
        short8 Bv = __builtin_bit_cast(short8, bv);
        accX = __builtin_amdgcn_mfma_f32_32x32x16_bf16(Av, Bv, accX, 0, 0, 0);
        accS = __builtin_amdgcn_mfma_f32_32x32x16_bf16(Qv, Bv, accS, 0, 0, 0);
    };

    f32x4 xa0 = *(const f32x4*)(xp),      xb0 = *(const f32x4*)(xp + 4);
    u32x4 wa0 = *(const u32x4*)(wp),      wb0 = *(const u32x4*)(wp + 4);
    f32x4 xa1 = *(const f32x4*)(xp + 16), xb1 = *(const f32x4*)(xp + 20);
    u32x4 wa1 = *(const u32x4*)(wp + 16), wb1 = *(const u32x4*)(wp + 20);
#pragma unroll
    for (int s = 0; s < KST; s += 2){
        f32x4 XA = xa0, XB = xb0; u32x4 WA = wa0, WB = wb0;
        if (s + 2 < KST){
            xa0 = *(const f32x4*)(xp + (s+2)*16);      xb0 = *(const f32x4*)(xp + (s+2)*16 + 4);
            wa0 = *(const u32x4*)(wp + (s+2)*16);      wb0 = *(const u32x4*)(wp + (s+2)*16 + 4);
        }
        step(XA, XB, WA, WB);
        XA = xa1; XB = xb1; WA = wa1; WB = wb1;
        if (s + 3 < KST){
            xa1 = *(const f32x4*)(xp + (s+3)*16);      xb1 = *(const f32x4*)(xp + (s+3)*16 + 4);
            wa1 = *(const u32x4*)(wp + (s+3)*16);      wb1 = *(const u32x4*)(wp + (s+3)*16 + 4);
        }
        step(XA, XB, WA, WB);
    }

    size_t pb = (((size_t)b * NCH + chunk) * NTL + wave) * 1024;
#pragma unroll
    for (int p = 0; p < 4; p++){
        uint2 vx = make_uint2(pkt(accX[4*p], accX[4*p+1]), pkt(accX[4*p+2], accX[4*p+3]));
        uint2 vs = make_uint2(pkt(accS[4*p], accS[4*p+1]), pkt(accS[4*p+2], accS[4*p+3]));
        *(uint2*)(Ppart + pb + p*128 + lane*2) = vx;
        *(uint2*)(Ppart + pb + 512 + p*128 + lane*2) = vs;
    }
    lqacc += __shfl_xor(lqacc, 32);
    if (lane < 32) Plq[(((size_t)b * NCH + chunk) * NTL + wave) * 32 + lane] = lqacc;
}

// ---- reduce bf16 partials -> Xg/Sg/lqs ----
__global__ __launch_bounds__(256) void k_reduce(const u32* __restrict__ P, const float* __restrict__ Plq,
                                                float* __restrict__ Xg, float* __restrict__ Sg,
                                                float* __restrict__ lqs){
    int g = blockIdx.x;                   // [BS * NTL * RSUB] = 512
    int sub = g % RSUB;
    int tile = (g / RSUB) % NTL;
    int b = g / (RSUB * NTL);
    int t = threadIdx.x;
    f32x4 ax = {0,0,0,0}, as = {0,0,0,0};
    for (int i = 0; i < RCH; i++){
        int ch = sub * RCH + i;
        const u32* base = P + (((size_t)b * NCH + ch) * NTL + tile) * 1024;
        uint2 ux = *(const uint2*)(base + t*2);
        uint2 us = *(const uint2*)(base + 512 + t*2);
        ax[0] += bflo(ux.x); ax[1] += bfhi(ux.x); ax[2] += bflo(ux.y); ax[3] += bfhi(ux.y);
        as[0] += bflo(us.x); as[1] += bfhi(us.x); as[2] += bflo(us.y); as[3] += bfhi(us.y);
    }
    int p = t >> 6, l = t & 63;
    int col = l & 31;
#pragma unroll
    for (int j = 0; j < 4; j++){
        int row32 = j + 8*p + 4*(l >> 5);
        size_t o = ((size_t)b * NR2 + tile*32 + row32) * 32 + col;
        atomicAdd(&Xg[o], ax[j]);
        atomicAdd(&Sg[o], as[j]);
    }
    if (t < 32){
        float s = 0.f;
        for (int i = 0; i < RCH; i++){
            int ch = sub * RCH + i;
            s += Plq[(((size_t)b * NCH + ch) * NTL + tile) * 32 + t];
        }
        atomicAdd(&lqs[b * NR2 + tile*32 + t], s);
    }
}

// ---- register-resident Jonker-Volgenant (f32) + losses (1 wave per image) ----
// Unique-optimum argument: random continuous costs -> optimal assignment is
// unique, so any exact LSA (incl. f32 duals at these margins) = reference's.
__global__ __launch_bounds__(64) void k_match(const float* __restrict__ cl, const int* __restrict__ gtc,
                                              const float* __restrict__ Xg, const float* __restrict__ Sg,
                                              const float* __restrict__ lqs, float* __restrict__ out){
    __shared__ float c[MG][NQ];           // 8 KB
    int b = blockIdx.x, t = threadIdx.x;
    bool hasB = (t < NQ - 64);            // t < 36

    // phase 1: cost (same f32 math as r3-r13)
    for (int q = t; q < NQ; q += 64){
        const float* lg = cl + ((size_t)b * NQ + q) * C1;
        float l0=lg[0],l1=lg[1],l2=lg[2],l3=lg[3],l4=lg[4],l5=lg[5],l6=lg[6];
        float mx = fmaxf(fmaxf(fmaxf(l0,l1),fmaxf(l2,l3)), fmaxf(fmaxf(l4,l5),l6));
        float e0=__expf(l0-mx),e1=__expf(l1-mx),e2=__expf(l2-mx),e3=__expf(l3-mx),
              e4=__expf(l4-mx),e5=__expf(l5-mx),e6=__expf(l6-mx);
        float inv = 1.0f / (e0+e1+e2+e3+e4+e5+e6);
        float lqv = lqs[b * NR2 + q];
        float psv = Sg[((size_t)b * NR2 + q) * 32 + 20];
#pragma unroll
        for (int m = 0; m < MG; m++){
            int cc = gtc[b * MG + m];
            float ec = (cc==0)?e0:(cc==1)?e1:(cc==2)?e2:(cc==3)?e3:(cc==4)?e4:e5;
            float Xv = Xg[((size_t)b * NR2 + q) * 32 + m];
            float Sv = Sg[((size_t)b * NR2 + q) * 32 + m];
            float ysm = Xg[((size_t)b * NR2 + 100) * 32 + m];
            float bce = -(Xv + lqv) * (1.0f / (float)HWPX);
            float dice = 1.0f - (2.0f * Sv + 1.0f) / (psv + ysm + 1.0f);
            c[m][q] = 2.0f * (-ec * inv) + 5.0f * bce + 5.0f * dice;
        }
    }
    __syncthreads();

    // phase 2: JV in registers, all-f32 state
    const float INF = 1e30f;
    float vA = 0.0f, vB = 0.0f, u_r = 0.0f;
    int pA = 0, pB = 0;

    for (int i = 1; i <= MG; i++){
        float minvA = INF, minvB = INF;
        int wayA = 0, wayB = 0;
        bool usedA = false, usedB = false;
        bool inTree = (t == i - 1);
        int j0 = 0, i0 = i;
        while (true){
            inTree = inTree || (t == i0 - 1);
            float du = __shfl(u_r, i0 - 1);
            const float* crow = &c[i0 - 1][0];
            float cA = crow[t];
            float cB = hasB ? crow[t + 64] : 0.0f;
            float candA = cA - du - vA;
            float candB = cB - du - vB;
            if (!usedA && candA < minvA){ minvA = candA; wayA = j0; }
            if (hasB && !usedB && candB < minvB){ minvB = candB; wayB = j0; }
            // argmin over unused cols (first-index tie-break)
            float mA = usedA ? INF : minvA;
            float mB = (hasB && !usedB) ? minvB : INF;
            float best = mA; int bcol = t + 1;
            if (mB < best){ best = mB; bcol = t + 65; }
#pragma unroll
            for (int off = 32; off; off >>= 1){
                float ob = __shfl_xor(best, off);
                int   oc = __shfl_xor(bcol, off);
                if (ob < best || (ob == best && oc < bcol)){ best = ob; bcol = oc; }
            }
            float delta = best;
            int j1 = bcol;
            if (inTree) u_r += delta;
            if (usedA) vA -= delta; else minvA -= delta;
            if (hasB){ if (usedB) vB -= delta; else minvB -= delta; }
            j0 = j1;
            usedA = usedA || (t == j0 - 1);
            usedB = usedB || (t == j0 - 65);
            int own = (j0 <= 64) ? (j0 - 1) : (j0 - 65);
            int pj = __shfl((j0 <= 64) ? pA : pB, own);
            if (pj == 0) break;
            i0 = pj;
        }
        // augment
        int cur = j0;
        while (cur){
            int own = (cur <= 64) ? (cur - 1) : (cur - 65);
            int w = __shfl((cur <= 64) ? wayA : wayB, own);
            int pv;
            if (w == 0) pv = i;
            else {
                int own2 = (w <= 64) ? (w - 1) : (w - 65);
                pv = __shfl((w <= 64) ? pA : pB, own2);
            }
            if (cur <= 64){ if (t == cur - 1) pA = pv; }
            else          { if (t == cur - 65) pB = pv; }
            cur = w;
        }
    }

    // phase 3: losses; lane handles q=t (pA) and q=t+64 (pB)
    float wnll = 0.f, wsum = 0.f, bsum = 0.f, dsum = 0.f;
#pragma unroll
    for (int slot = 0; slot < 2; slot++){
        int q = t + slot * 64;
        if (q >= NQ) break;
        int pi = slot ? pB : pA;
        int tg = (pi != 0) ? gtc[b * MG + (pi - 1)] : NO_OBJ_C;
        const float* lg = cl + ((size_t)b * NQ + q) * C1;
        float l0=lg[0],l1=lg[1],l2=lg[2],l3=lg[3],l4=lg[4],l5=lg[5],l6=lg[6];
        float mx = fmaxf(fmaxf(fmaxf(l0,l1),fmaxf(l2,l3)), fmaxf(fmaxf(l4,l5),l6));
        float se = __expf(l0-mx)+__expf(l1-mx)+__expf(l2-mx)+__expf(l3-mx)
                 + __expf(l4-mx)+__expf(l5-mx)+__expf(l6-mx);
        float lse = __logf(se) + mx;
        float lt = (tg==0)?l0:(tg==1)?l1:(tg==2)?l2:(tg==3)?l3:(tg==4)?l4:(tg==5)?l5:l6;
        float w = (tg == NO_OBJ_C) ? 0.1f : 1.0f;
        wnll += w * (lse - lt);
        wsum += w;
        if (pi != 0){
            int k = pi - 1;
            float Xv  = Xg[((size_t)b * NR2 + q) * 32 + k];
            float Sv  = Sg[((size_t)b * NR2 + q) * 32 + k];
            float lqv = lqs[b * NR2 + q];
            float psv = Sg[((size_t)b * NR2 + q) * 32 + 20];
            float ysm = Xg[((size_t)b * NR2 + 100) * 32 + k];
            bsum += -(Xv + lqv);
            dsum += 1.0f - (2.0f * Sv + 1.0f) / (psv + ysm + 1.0f);
        }
    }
#pragma unroll
    for (int off = 32; off; off >>= 1){
        wnll += __shfl_xor(wnll, off);
        wsum += __shfl_xor(wsum, off);
        bsum += __shfl_xor(bsum, off);
        dsum += __shfl_xor(dsum, off);
    }
    if (t == 0){
        float tc = wnll / wsum;
        float tm = bsum / ((float)MG * (float)HWPX);
        float td = dsum / (float)MG;
        atomicAdd(&out[0], 0.5f * tc);
        atomicAdd(&out[1], 0.5f * tm);
        atomicAdd(&out[2], 0.5f * td);
        atomicAdd(&out[3], 0.5f * (2.0f * tc + 5.0f * tm + 5.0f * td));
    }
}

extern "C" void kernel_launch(void* const* d_in, const int* in_sizes, int n_in,
                              void* d_out, int out_size, void* d_ws, size_t ws_size,
                              hipStream_t stream){
    const float* cls_logits  = (const float*)d_in[0];
    const float* mask_logits = (const float*)d_in[1];
    const int*   gt_classes  = (const int*)d_in[2];
    const int*   gt_masks    = (const int*)d_in[3];
    float* out = (float*)d_out;
    char* ws = (char*)d_ws;

    u32*   packed = (u32*)  (ws + OFF_PACKED);
    u32*   Ppart  = (u32*)  (ws + OFF_P);
    float* Plq    = (float*)(ws + OFF_PLQ);
    float* Xg     = (float*)(ws + OFF_X);
    float* Sg     = (float*)(ws + OFF_S);
    float* lqs    = (float*)(ws + OFF_LQS);

    k_pack  <<<dim3(BS * HWPX / 1024), dim3(256), 0, stream>>>(gt_masks, packed, Xg, out);
    k_main  <<<dim3(BS * NCH),         dim3(256), 0, stream>>>(mask_logits, packed, Ppart, Plq);
    k_reduce<<<dim3(BS * NTL * RSUB),  dim3(256), 0, stream>>>(Ppart, Plq, Xg, Sg, lqs);
    k_match <<<dim3(BS),               dim3(64),  0, stream>>>(cls_logits, gt_classes, Xg, Sg, lqs, out);
}